// Round 1
// baseline (271.965 us; speedup 1.0000x reference)
//
#include <hip/hip_runtime.h>

#define B_ 8
#define L_ 2048
#define CIN_ 256
#define COUT_ 256
#define HEADS_ 4
#define HD_ 64
#define NEG_SLOPE_ 0.2f
#define LOG2E_ 1.4426950408889634f

#define TI 32   // proj i-rows per block
#define TJ 64   // attn j-cols per tile
#define NJT (L_ / TJ)

typedef __attribute__((ext_vector_type(4))) float f32x4;
typedef __attribute__((ext_vector_type(2))) float f32x2;
typedef __attribute__((ext_vector_type(8))) __bf16 bf16x8;
typedef __attribute__((ext_vector_type(4))) __bf16 bf16x4;

// MFMA 16x16x32 bf16 layouts (m89/m120-verified):
//  A[m][k]: m = lane&15, k = (lane>>4)*8 + e
//  B[k][n]: n = lane&15, k = (lane>>4)*8 + e
//  D[m][n]: n = lane&15, m = (lane>>4)*4 + reg
//
// hF ("B-frag-linear" h): for (b,h,jt,kt,nt) a 512-elem block, element
// (q*16+col)*8+e = h[channel h*64+nt*16+col][j = jt*64+kt*32+q*8+e].
// Rank-1 factorization: exp(leaky(a_i+d_j)) = max(E_i*F_j, E'_i*F'_j) — exact.
// abitsT transposed masks: abitsT[b][jw][row] (jw = j/64).

// ---------------------------------------------------------------------------
// Kernel 0: pack adj int32 -> 1 bit, TRANSPOSED layout abitsT[b][jw][row].
// ---------------------------------------------------------------------------
__global__ __launch_bounds__(256, 4)
void pack_kernel(const int* __restrict__ adj, unsigned long long* __restrict__ abitsT) {
  const size_t wid = ((size_t)blockIdx.x * 256 + threadIdx.x) >> 6;  // 256-int chunk
  const int lane = threadIdx.x & 63;
  const int* p = adj + wid * 256 + lane;
  unsigned long long b0 = __ballot(p[0]   != 0);
  unsigned long long b1 = __ballot(p[64]  != 0);
  unsigned long long b2 = __ballot(p[128] != 0);
  unsigned long long b3 = __ballot(p[192] != 0);
  if (lane == 0) {
    const size_t row = wid >> 3;           // global row = b*2048 + i
    const int jw0 = (int)(wid & 7) * 4;    // first j-word of this chunk
    const size_t bb = row >> 11, l = row & 2047;
    unsigned long long* dst = abitsT + (bb << 16) + l;   // b*32*2048 + i
    dst[(size_t)(jw0 + 0) << 11] = b0;
    dst[(size_t)(jw0 + 1) << 11] = b1;
    dst[(size_t)(jw0 + 2) << 11] = b2;
    dst[(size_t)(jw0 + 3) << 11] = b3;
  }
}

// ---------------------------------------------------------------------------
// Kernel 1: h = x@W^T via MFMA -> hF (B-frag-linear bf16) + (E,E')/(F,F')
// factor pairs. grid 512 x 256 thr; block = 32 seq rows, wave w = head w.
// ---------------------------------------------------------------------------
__global__ __launch_bounds__(256, 2)
void proj_kernel(const float* __restrict__ x, const float* __restrict__ W,
                 const float* __restrict__ att_src, const float* __restrict__ att_dst,
                 __bf16* __restrict__ hF, float2* __restrict__ aE,
                 float2* __restrict__ aF) {
  __shared__ __align__(16) __bf16 Wl[COUT_][80];
  __shared__ __align__(16) __bf16 Al[2][2][512];

  const int tid = threadIdx.x;
  const int r0 = blockIdx.x * TI;
  const int b  = r0 >> 11;
  const int l0 = r0 & (L_ - 1);

  const int w = tid >> 6, lane = tid & 63, col = lane & 15, q = lane >> 4;
  const int si = tid >> 3, soct = tid & 7;
  const int wn = tid >> 2, wkq = tid & 3;

  f32x4 acc[2][4];
#pragma unroll
  for (int mt = 0; mt < 2; ++mt)
#pragma unroll
    for (int nt = 0; nt < 4; ++nt) acc[mt][nt] = (f32x4)0.f;

  for (int kc = 0; kc < CIN_ / 64; ++kc) {
    __syncthreads();
#pragma unroll
    for (int rg = 0; rg < 4; ++rg) {
      const int row = rg * 64 + wn;
      const float4* ws = (const float4*)(W + (size_t)row * CIN_ + kc * 64 + wkq * 16);
#pragma unroll
      for (int u = 0; u < 4; ++u) {
        float4 f = ws[u];
        bf16x4 v;
        v[0] = (__bf16)f.x; v[1] = (__bf16)f.y; v[2] = (__bf16)f.z; v[3] = (__bf16)f.w;
        *(bf16x4*)&Wl[row][wkq * 16 + u * 4] = v;
      }
    }
    {
      const float4* xs = (const float4*)(x + (size_t)(r0 + si) * CIN_ + kc * 64 + soct * 8);
      float4 f0 = xs[0], f1 = xs[1];
      bf16x8 v;
      v[0] = (__bf16)f0.x; v[1] = (__bf16)f0.y; v[2] = (__bf16)f0.z; v[3] = (__bf16)f0.w;
      v[4] = (__bf16)f1.x; v[5] = (__bf16)f1.y; v[6] = (__bf16)f1.z; v[7] = (__bf16)f1.w;
      *(bf16x8*)&Al[si >> 4][soct >> 2][(((soct & 3) << 4) + (si & 15)) << 3] = v;
    }
    __syncthreads();

    bf16x8 af[2][2], bfr[2][4];
#pragma unroll
    for (int mt = 0; mt < 2; ++mt)
#pragma unroll
      for (int kt = 0; kt < 2; ++kt)
        af[mt][kt] = *(const bf16x8*)&Al[mt][kt][lane << 3];
#pragma unroll
    for (int kt = 0; kt < 2; ++kt)
#pragma unroll
      for (int nt = 0; nt < 4; ++nt)
        bfr[kt][nt] = *(const bf16x8*)&Wl[w * 64 + nt * 16 + col][kt * 32 + q * 8];
#pragma unroll
    for (int kt = 0; kt < 2; ++kt)
#pragma unroll
      for (int mt = 0; mt < 2; ++mt)
#pragma unroll
        for (int nt = 0; nt < 4; ++nt)
          acc[mt][nt] = __builtin_amdgcn_mfma_f32_16x16x32_bf16(
              af[mt][kt], bfr[kt][nt], acc[mt][nt], 0, 0, 0);
  }

  // ---- fused score factors ----
  float asv[4], adv[4];
#pragma unroll
  for (int nt = 0; nt < 4; ++nt) {
    asv[nt] = att_src[w * 64 + nt * 16 + col];
    adv[nt] = att_dst[w * 64 + nt * 16 + col];
  }
#pragma unroll
  for (int mt = 0; mt < 2; ++mt)
#pragma unroll
    for (int reg = 0; reg < 4; ++reg) {
      float s = 0.f, d = 0.f;
#pragma unroll
      for (int nt = 0; nt < 4; ++nt) {
        s = fmaf(acc[mt][nt][reg], asv[nt], s);
        d = fmaf(acc[mt][nt][reg], adv[nt], d);
      }
      s += __shfl_xor(s, 1, 64); d += __shfl_xor(d, 1, 64);
      s += __shfl_xor(s, 2, 64); d += __shfl_xor(d, 2, 64);
      s += __shfl_xor(s, 4, 64); d += __shfl_xor(d, 4, 64);
      s += __shfl_xor(s, 8, 64); d += __shfl_xor(d, 8, 64);
      if (col == 0) {
        int il = mt * 16 + q * 4 + reg;
        const size_t idx = ((size_t)(b * HEADS_ + w) << 11) + l0 + il;
        float2 ev, fv;
        ev.x = __builtin_exp2f(s * LOG2E_);
        ev.y = __builtin_exp2f(s * (LOG2E_ * NEG_SLOPE_));
        fv.x = __builtin_exp2f(d * LOG2E_);
        fv.y = __builtin_exp2f(d * (LOG2E_ * NEG_SLOPE_));
        aE[idx] = ev;
        aF[idx] = fv;
      }
    }

  // ---- hF write: D-frag -> B-frag-linear ----
  {
    const int jt_p = l0 >> 6;
    const int kt_p = (l0 >> 5) & 1;
    const int qhi = q >> 1, qlo = q & 1;
#pragma unroll
    for (int mt = 0; mt < 2; ++mt) {
      const int qp = mt * 2 + qhi;
#pragma unroll
      for (int nt = 0; nt < 4; ++nt) {
        bf16x4 v;
        v[0] = (__bf16)acc[mt][nt][0];
        v[1] = (__bf16)acc[mt][nt][1];
        v[2] = (__bf16)acc[mt][nt][2];
        v[3] = (__bf16)acc[mt][nt][3];
        const size_t off =
            ((((size_t)(b * HEADS_ + w) * 32 + jt_p) * 2 + kt_p) * 4 + nt) * 512 +
            (qp * 16 + col) * 8 + qlo * 4;
        *(bf16x4*)(hF + off) = v;
      }
    }
  }
}

// ---------------------------------------------------------------------------
// Kernel 2 (R13): split-j attention.
//  * __launch_bounds__(512, 2): this toolchain's arg-2 is blocks/CU (R11's
//    (512,4) produced a 64-VGPR budget => 8 waves/SIMD semantics). 2 blocks/CU
//    = 4 waves/SIMD = 128-VGPR cap; kt-loop live set ~112 so no spill expected.
//    Without the cap the compiler can exceed 128 => 1 block/CU => latency-bound.
//  * av build: v_pk_mul_f32 (both exp branches, 1 op), v_max, then mask via
//    sbfe sign-smear + bit-AND (exact 0.0f for non-edges). ~6.5 -> ~4.5
//    VALU/elem on the dominant loop.
// ---------------------------------------------------------------------------
__global__ __launch_bounds__(512, 2)
void attn_kernel(const __bf16* __restrict__ hF, const float2* __restrict__ aE,
                 const float2* __restrict__ aF,
                 const unsigned long long* __restrict__ abitsT,
                 float* __restrict__ out) {
  __shared__ __align__(16) float comb[HEADS_][64][40];   // 40 KB combine buf

  const int tid = threadIdx.x;
  const int b  = blockIdx.x & 7;           // XCD swizzle
  const int i0 = (blockIdx.x >> 3) * 32;

  const int w = tid >> 6, lane = tid & 63, col = lane & 15, q = lane >> 4;
  const int hh = w & 3;                    // head
  const int jh = w >> 2;                   // j-half
  const int jt0 = jh * (NJT / 2), jt1 = jt0 + NJT / 2;

  const size_t hl = (size_t)(b * HEADS_ + hh);
  const float2 EE0 = aE[(hl << 11) + i0 + col];
  const float2 EE1 = aE[(hl << 11) + i0 + 16 + col];
  const f32x2 Epair[2] = {{EE0.x, EE0.y}, {EE1.x, EE1.y}};
  const float* afb = (const float*)(aF + (hl << 11)) + q * 16;
  const __bf16* hb = hF + hl * 131072 + lane * 8;
  const unsigned long long* mb = abitsT + ((size_t)b << 16) + i0 + col;

  bf16x8 bones;
#pragma unroll
  for (int e = 0; e < 8; ++e) bones[e] = (__bf16)1.0f;

  f32x4 acc[2][4], accl[2];
#pragma unroll
  for (int mt = 0; mt < 2; ++mt) {
    accl[mt] = (f32x4)0.f;
#pragma unroll
    for (int nt = 0; nt < 4; ++nt) acc[mt][nt] = (f32x4)0.f;
  }

  unsigned long long cm0 = mb[(size_t)jt0 << 11];
  unsigned long long cm1 = mb[((size_t)jt0 << 11) + 16];

  for (int jt = jt0; jt < jt1; ++jt) {
    const int jn = (jt < jt1 - 1) ? jt + 1 : jt;
    const unsigned long long nm0 = mb[(size_t)jn << 11];
    const unsigned long long nm1 = mb[((size_t)jn << 11) + 16];

    // per-kt: load 4 cb frags + 8 cf pairs, build av for both mt, 10 MFMAs.
#pragma unroll
    for (int kt = 0; kt < 2; ++kt) {
      bf16x8 cb0 = *(const bf16x8*)(hb + jt * 4096 + (kt * 4 + 0) * 512);
      bf16x8 cb1 = *(const bf16x8*)(hb + jt * 4096 + (kt * 4 + 1) * 512);
      bf16x8 cb2 = *(const bf16x8*)(hb + jt * 4096 + (kt * 4 + 2) * 512);
      bf16x8 cb3 = *(const bf16x8*)(hb + jt * 4096 + (kt * 4 + 3) * 512);
      f32x2 cfp[8];
#pragma unroll
      for (int u = 0; u < 4; ++u) {
        float4 t = *(const float4*)(afb + jt * 128 + kt * 64 + u * 4);
        cfp[u * 2]     = (f32x2){t.x, t.y};
        cfp[u * 2 + 1] = (f32x2){t.z, t.w};
      }

      bf16x8 av[2];
#pragma unroll
      for (int mt = 0; mt < 2; ++mt) {
        const unsigned long long bw = mt ? cm1 : cm0;
        const int tsh = (int)(((unsigned int)(bw >> (kt * 32))) >> (q * 8));
        const f32x2 Ep = Epair[mt];
#pragma unroll
        for (int e = 0; e < 8; ++e) {
          f32x2 prod;
          asm("v_pk_mul_f32 %0, %1, %2" : "=v"(prod) : "v"(Ep), "v"(cfp[e]));
          float pm = fmaxf(prod.x, prod.y);
          const int smear = __builtin_amdgcn_sbfe(tsh, e, 1);  // bit -> 0/-1
          pm = __builtin_bit_cast(float,
                                  __builtin_bit_cast(int, pm) & smear);
          av[mt][e] = (__bf16)pm;
        }
      }
#pragma unroll
      for (int mt = 0; mt < 2; ++mt) {
        acc[mt][0] = __builtin_amdgcn_mfma_f32_16x16x32_bf16(av[mt], cb0, acc[mt][0], 0, 0, 0);
        acc[mt][1] = __builtin_amdgcn_mfma_f32_16x16x32_bf16(av[mt], cb1, acc[mt][1], 0, 0, 0);
        acc[mt][2] = __builtin_amdgcn_mfma_f32_16x16x32_bf16(av[mt], cb2, acc[mt][2], 0, 0, 0);
        acc[mt][3] = __builtin_amdgcn_mfma_f32_16x16x32_bf16(av[mt], cb3, acc[mt][3], 0, 0, 0);
        accl[mt] = __builtin_amdgcn_mfma_f32_16x16x32_bf16(av[mt], bones, accl[mt], 0, 0, 0);
      }
    }

    cm0 = nm0; cm1 = nm1;
  }

  // ---- combine j-halves via LDS ----
  if (jh == 1) {
#pragma unroll
    for (int mt = 0; mt < 2; ++mt)
#pragma unroll
      for (int nt = 0; nt < 4; ++nt)
        *(f32x4*)&comb[hh][lane][mt * 16 + nt * 4] = acc[mt][nt];
    *(f32x4*)&comb[hh][lane][32] = accl[0];
    *(f32x4*)&comb[hh][lane][36] = accl[1];
  }
  __syncthreads();
  if (jh == 0) {
#pragma unroll
    for (int mt = 0; mt < 2; ++mt) {
      const f32x4 lo = accl[mt] + *(const f32x4*)&comb[hh][lane][32 + mt * 4];
#pragma unroll
      for (int reg = 0; reg < 4; ++reg) {
        const int m = q * 4 + reg;
        const float linv = 1.0f / lo[reg];
        const size_t orow =
            ((size_t)(b * L_ + i0 + mt * 16 + m)) * COUT_ + hh * 64;
#pragma unroll
        for (int nt = 0; nt < 4; ++nt) {
          const float v =
              acc[mt][nt][reg] + comb[hh][lane][mt * 16 + nt * 4 + reg];
          out[orow + nt * 16 + col] = v * linv;
        }
      }
    }
  }
}

// ---------------------------------------------------------------------------
extern "C" void kernel_launch(void* const* d_in, const int* in_sizes, int n_in,
                              void* d_out, int out_size, void* d_ws, size_t ws_size,
                              hipStream_t stream) {
  const float* x       = (const float*)d_in[0];
  const int*   adj     = (const int*)d_in[1];
  const float* W       = (const float*)d_in[2];
  const float* att_src = (const float*)d_in[3];
  const float* att_dst = (const float*)d_in[4];
  float* out = (float*)d_out;

  char* ws = (char*)d_ws;
  __bf16* hF = (__bf16*)ws;                                   // 8 MB frag-linear
  float2* aE = (float2*)(ws + (8u << 20));                    // 512 KB (E,E')
  float2* aF = (float2*)(ws + (9u << 20));                    // 512 KB (F,F')
  unsigned long long* abitsT =
      (unsigned long long*)(ws + (10u << 20));                // 4 MB transposed

  pack_kernel<<<(B_ * L_ * (L_ / 256)) / 4, 256, 0, stream>>>(adj, abitsT);
  proj_kernel<<<(B_ * L_) / TI, 256, 0, stream>>>(x, W, att_src, att_dst, hF, aE, aF);
  attn_kernel<<<B_ * (L_ / 32), 512, 0, stream>>>(hF, aE, aF, abitsT, out);
}

// Round 2
// 267.097 us; speedup vs baseline: 1.0182x; 1.0182x over previous
//
#include <hip/hip_runtime.h>

#define B_ 8
#define L_ 2048
#define CIN_ 256
#define COUT_ 256
#define HEADS_ 4
#define HD_ 64
#define NEG_SLOPE_ 0.2f
#define LOG2E_ 1.4426950408889634f

#define TI 32   // proj i-rows per block
#define TJ 64   // attn j-cols per tile
#define NJT (L_ / TJ)

typedef __attribute__((ext_vector_type(4))) float f32x4;
typedef __attribute__((ext_vector_type(8))) __bf16 bf16x8;
typedef __attribute__((ext_vector_type(4))) __bf16 bf16x4;

// MFMA 16x16x32 bf16 layouts (m89/m120-verified):
//  A[m][k]: m = lane&15, k = (lane>>4)*8 + e
//  B[k][n]: n = lane&15, k = (lane>>4)*8 + e
//  D[m][n]: n = lane&15, m = (lane>>4)*4 + reg
//
// hF ("B-frag-linear" h): for (b,h,jt,kt,nt) a 512-elem block, element
// (q*16+col)*8+e = h[channel h*64+nt*16+col][j = jt*64+kt*32+q*8+e].
// Rank-1 factorization: exp(leaky(a_i+d_j)) = max(E_i*F_j, E'_i*F'_j) — exact.
// abitsT transposed masks: abitsT[b][jw][row] (jw = j/64).

// ---------------------------------------------------------------------------
// Kernel 0: pack adj int32 -> 1 bit, TRANSPOSED layout abitsT[b][jw][row].
// ---------------------------------------------------------------------------
__global__ __launch_bounds__(256, 4)
void pack_kernel(const int* __restrict__ adj, unsigned long long* __restrict__ abitsT) {
  const size_t wid = ((size_t)blockIdx.x * 256 + threadIdx.x) >> 6;  // 256-int chunk
  const int lane = threadIdx.x & 63;
  const int* p = adj + wid * 256 + lane;
  unsigned long long b0 = __ballot(p[0]   != 0);
  unsigned long long b1 = __ballot(p[64]  != 0);
  unsigned long long b2 = __ballot(p[128] != 0);
  unsigned long long b3 = __ballot(p[192] != 0);
  if (lane == 0) {
    const size_t row = wid >> 3;           // global row = b*2048 + i
    const int jw0 = (int)(wid & 7) * 4;    // first j-word of this chunk
    const size_t bb = row >> 11, l = row & 2047;
    unsigned long long* dst = abitsT + (bb << 16) + l;   // b*32*2048 + i
    dst[(size_t)(jw0 + 0) << 11] = b0;
    dst[(size_t)(jw0 + 1) << 11] = b1;
    dst[(size_t)(jw0 + 2) << 11] = b2;
    dst[(size_t)(jw0 + 3) << 11] = b3;
  }
}

// ---------------------------------------------------------------------------
// Kernel 1: h = x@W^T via MFMA -> hF (B-frag-linear bf16) + (E,E')/(F,F')
// factor pairs. grid 512 x 256 thr; block = 32 seq rows, wave w = head w.
// ---------------------------------------------------------------------------
__global__ __launch_bounds__(256, 2)
void proj_kernel(const float* __restrict__ x, const float* __restrict__ W,
                 const float* __restrict__ att_src, const float* __restrict__ att_dst,
                 __bf16* __restrict__ hF, float2* __restrict__ aE,
                 float2* __restrict__ aF) {
  __shared__ __align__(16) __bf16 Wl[COUT_][80];
  __shared__ __align__(16) __bf16 Al[2][2][512];

  const int tid = threadIdx.x;
  const int r0 = blockIdx.x * TI;
  const int b  = r0 >> 11;
  const int l0 = r0 & (L_ - 1);

  const int w = tid >> 6, lane = tid & 63, col = lane & 15, q = lane >> 4;
  const int si = tid >> 3, soct = tid & 7;
  const int wn = tid >> 2, wkq = tid & 3;

  f32x4 acc[2][4];
#pragma unroll
  for (int mt = 0; mt < 2; ++mt)
#pragma unroll
    for (int nt = 0; nt < 4; ++nt) acc[mt][nt] = (f32x4)0.f;

  for (int kc = 0; kc < CIN_ / 64; ++kc) {
    __syncthreads();
#pragma unroll
    for (int rg = 0; rg < 4; ++rg) {
      const int row = rg * 64 + wn;
      const float4* ws = (const float4*)(W + (size_t)row * CIN_ + kc * 64 + wkq * 16);
#pragma unroll
      for (int u = 0; u < 4; ++u) {
        float4 f = ws[u];
        bf16x4 v;
        v[0] = (__bf16)f.x; v[1] = (__bf16)f.y; v[2] = (__bf16)f.z; v[3] = (__bf16)f.w;
        *(bf16x4*)&Wl[row][wkq * 16 + u * 4] = v;
      }
    }
    {
      const float4* xs = (const float4*)(x + (size_t)(r0 + si) * CIN_ + kc * 64 + soct * 8);
      float4 f0 = xs[0], f1 = xs[1];
      bf16x8 v;
      v[0] = (__bf16)f0.x; v[1] = (__bf16)f0.y; v[2] = (__bf16)f0.z; v[3] = (__bf16)f0.w;
      v[4] = (__bf16)f1.x; v[5] = (__bf16)f1.y; v[6] = (__bf16)f1.z; v[7] = (__bf16)f1.w;
      *(bf16x8*)&Al[si >> 4][soct >> 2][(((soct & 3) << 4) + (si & 15)) << 3] = v;
    }
    __syncthreads();

    bf16x8 af[2][2], bfr[2][4];
#pragma unroll
    for (int mt = 0; mt < 2; ++mt)
#pragma unroll
      for (int kt = 0; kt < 2; ++kt)
        af[mt][kt] = *(const bf16x8*)&Al[mt][kt][lane << 3];
#pragma unroll
    for (int kt = 0; kt < 2; ++kt)
#pragma unroll
      for (int nt = 0; nt < 4; ++nt)
        bfr[kt][nt] = *(const bf16x8*)&Wl[w * 64 + nt * 16 + col][kt * 32 + q * 8];
#pragma unroll
    for (int kt = 0; kt < 2; ++kt)
#pragma unroll
      for (int mt = 0; mt < 2; ++mt)
#pragma unroll
        for (int nt = 0; nt < 4; ++nt)
          acc[mt][nt] = __builtin_amdgcn_mfma_f32_16x16x32_bf16(
              af[mt][kt], bfr[kt][nt], acc[mt][nt], 0, 0, 0);
  }

  // ---- fused score factors ----
  float asv[4], adv[4];
#pragma unroll
  for (int nt = 0; nt < 4; ++nt) {
    asv[nt] = att_src[w * 64 + nt * 16 + col];
    adv[nt] = att_dst[w * 64 + nt * 16 + col];
  }
#pragma unroll
  for (int mt = 0; mt < 2; ++mt)
#pragma unroll
    for (int reg = 0; reg < 4; ++reg) {
      float s = 0.f, d = 0.f;
#pragma unroll
      for (int nt = 0; nt < 4; ++nt) {
        s = fmaf(acc[mt][nt][reg], asv[nt], s);
        d = fmaf(acc[mt][nt][reg], adv[nt], d);
      }
      s += __shfl_xor(s, 1, 64); d += __shfl_xor(d, 1, 64);
      s += __shfl_xor(s, 2, 64); d += __shfl_xor(d, 2, 64);
      s += __shfl_xor(s, 4, 64); d += __shfl_xor(d, 4, 64);
      s += __shfl_xor(s, 8, 64); d += __shfl_xor(d, 8, 64);
      if (col == 0) {
        int il = mt * 16 + q * 4 + reg;
        const size_t idx = ((size_t)(b * HEADS_ + w) << 11) + l0 + il;
        float2 ev, fv;
        ev.x = __builtin_exp2f(s * LOG2E_);
        ev.y = __builtin_exp2f(s * (LOG2E_ * NEG_SLOPE_));
        fv.x = __builtin_exp2f(d * LOG2E_);
        fv.y = __builtin_exp2f(d * (LOG2E_ * NEG_SLOPE_));
        aE[idx] = ev;
        aF[idx] = fv;
      }
    }

  // ---- hF write: D-frag -> B-frag-linear ----
  {
    const int jt_p = l0 >> 6;
    const int kt_p = (l0 >> 5) & 1;
    const int qhi = q >> 1, qlo = q & 1;
#pragma unroll
    for (int mt = 0; mt < 2; ++mt) {
      const int qp = mt * 2 + qhi;
#pragma unroll
      for (int nt = 0; nt < 4; ++nt) {
        bf16x4 v;
        v[0] = (__bf16)acc[mt][nt][0];
        v[1] = (__bf16)acc[mt][nt][1];
        v[2] = (__bf16)acc[mt][nt][2];
        v[3] = (__bf16)acc[mt][nt][3];
        const size_t off =
            ((((size_t)(b * HEADS_ + w) * 32 + jt_p) * 2 + kt_p) * 4 + nt) * 512 +
            (qp * 16 + col) * 8 + qlo * 4;
        *(bf16x4*)(hF + off) = v;
      }
    }
  }
}

// ---------------------------------------------------------------------------
// Kernel 2 (R14): split-j attention, R12 structure + kt-step software
// pipeline (T14 issue-early). Ping-pong register buffers cbA/cbB, cfA/cfB:
// while computing step s, the loads for step s+1 are in flight. VGPR-neutral
// vs R12 (R12 already held a full jt's 8 cb frags + 32 cf floats live).
// No inline asm (m240/T12: asm in the av-build path blocks the scheduler);
// no launch-bounds cap (R13's (512,2) regressed). Mask: 2-op sign-smear in
// plain C (bit -> 0/-1 -> bit-and, exact +0.0f for non-edges).
// ---------------------------------------------------------------------------
#define ATTN_STEP(CBC, CFC, CBN, CFN, JT, KT, JTN, KTN)                        \
  {                                                                            \
    _Pragma("unroll")                                                          \
    for (int u = 0; u < 4; ++u) {                                              \
      CBN[u] = *(const bf16x8*)(hb + (JTN) * 4096 + ((KTN) * 4 + u) * 512);    \
      CFN[u] = *(const f32x4*)(afb + (JTN) * 128 + (KTN) * 64 + u * 4);        \
    }                                                                          \
    bf16x8 av[2];                                                              \
    _Pragma("unroll")                                                          \
    for (int mt = 0; mt < 2; ++mt) {                                           \
      const unsigned long long bw = mt ? cm1 : cm0;                            \
      const unsigned int tsh = ((unsigned int)(bw >> ((KT) * 32))) >> (q * 8); \
      const float Ex = EE[mt].x, Ey = EE[mt].y;                                \
      _Pragma("unroll")                                                        \
      for (int e = 0; e < 8; ++e) {                                            \
        const float m1 = Ex * CFC[e >> 1][(e & 1) * 2];                        \
        const float m2 = Ey * CFC[e >> 1][(e & 1) * 2 + 1];                    \
        const float pm = fmaxf(m1, m2);                                        \
        const int sm = ((int)(tsh << (31 - e))) >> 31;                         \
        av[mt][e] = (__bf16)__builtin_bit_cast(                                \
            float, __builtin_bit_cast(int, pm) & sm);                          \
      }                                                                        \
    }                                                                          \
    _Pragma("unroll")                                                          \
    for (int mt = 0; mt < 2; ++mt) {                                           \
      acc[mt][0] = __builtin_amdgcn_mfma_f32_16x16x32_bf16(av[mt], CBC[0],     \
                                                           acc[mt][0], 0, 0, 0); \
      acc[mt][1] = __builtin_amdgcn_mfma_f32_16x16x32_bf16(av[mt], CBC[1],     \
                                                           acc[mt][1], 0, 0, 0); \
      acc[mt][2] = __builtin_amdgcn_mfma_f32_16x16x32_bf16(av[mt], CBC[2],     \
                                                           acc[mt][2], 0, 0, 0); \
      acc[mt][3] = __builtin_amdgcn_mfma_f32_16x16x32_bf16(av[mt], CBC[3],     \
                                                           acc[mt][3], 0, 0, 0); \
      accl[mt] = __builtin_amdgcn_mfma_f32_16x16x32_bf16(av[mt], bones,        \
                                                         accl[mt], 0, 0, 0);  \
    }                                                                          \
  }

__global__ __launch_bounds__(512)
void attn_kernel(const __bf16* __restrict__ hF, const float2* __restrict__ aE,
                 const float2* __restrict__ aF,
                 const unsigned long long* __restrict__ abitsT,
                 float* __restrict__ out) {
  __shared__ __align__(16) float comb[HEADS_][64][40];   // 40 KB combine buf

  const int tid = threadIdx.x;
  const int b  = blockIdx.x & 7;           // XCD swizzle
  const int i0 = (blockIdx.x >> 3) * 32;

  const int w = tid >> 6, lane = tid & 63, col = lane & 15, q = lane >> 4;
  const int hh = w & 3;                    // head
  const int jh = w >> 2;                   // j-half
  const int jt0 = jh * (NJT / 2), jt1 = jt0 + NJT / 2;

  const size_t hl = (size_t)(b * HEADS_ + hh);
  const float2 EE[2] = {aE[(hl << 11) + i0 + col],
                        aE[(hl << 11) + i0 + 16 + col]};
  const float* afb = (const float*)(aF + (hl << 11)) + q * 16;
  const __bf16* hb = hF + hl * 131072 + lane * 8;
  const unsigned long long* mb = abitsT + ((size_t)b << 16) + i0 + col;

  bf16x8 bones;
#pragma unroll
  for (int e = 0; e < 8; ++e) bones[e] = (__bf16)1.0f;

  f32x4 acc[2][4], accl[2];
#pragma unroll
  for (int mt = 0; mt < 2; ++mt) {
    accl[mt] = (f32x4)0.f;
#pragma unroll
    for (int nt = 0; nt < 4; ++nt) acc[mt][nt] = (f32x4)0.f;
  }

  unsigned long long cm0 = mb[(size_t)jt0 << 11];
  unsigned long long cm1 = mb[((size_t)jt0 << 11) + 16];

  // prologue: preload step (jt0, kt=0)
  bf16x8 cbA[4], cbB[4];
  f32x4 cfA[4], cfB[4];
#pragma unroll
  for (int u = 0; u < 4; ++u) {
    cbA[u] = *(const bf16x8*)(hb + jt0 * 4096 + u * 512);
    cfA[u] = *(const f32x4*)(afb + jt0 * 128 + u * 4);
  }

  for (int jt = jt0; jt < jt1; ++jt) {
    const int jn = (jt < jt1 - 1) ? jt + 1 : jt;
    const unsigned long long nm0 = mb[(size_t)jn << 11];
    const unsigned long long nm1 = mb[((size_t)jn << 11) + 16];

    // compute (jt,0) from A while prefetching (jt,1) into B
    ATTN_STEP(cbA, cfA, cbB, cfB, jt, 0, jt, 1);
    // compute (jt,1) from B while prefetching (jn,0) into A
    ATTN_STEP(cbB, cfB, cbA, cfA, jt, 1, jn, 0);

    cm0 = nm0; cm1 = nm1;
  }

  // ---- combine j-halves via LDS ----
  if (jh == 1) {
#pragma unroll
    for (int mt = 0; mt < 2; ++mt)
#pragma unroll
      for (int nt = 0; nt < 4; ++nt)
        *(f32x4*)&comb[hh][lane][mt * 16 + nt * 4] = acc[mt][nt];
    *(f32x4*)&comb[hh][lane][32] = accl[0];
    *(f32x4*)&comb[hh][lane][36] = accl[1];
  }
  __syncthreads();
  if (jh == 0) {
#pragma unroll
    for (int mt = 0; mt < 2; ++mt) {
      const f32x4 lo = accl[mt] + *(const f32x4*)&comb[hh][lane][32 + mt * 4];
#pragma unroll
      for (int reg = 0; reg < 4; ++reg) {
        const int m = q * 4 + reg;
        const float linv = 1.0f / lo[reg];
        const size_t orow =
            ((size_t)(b * L_ + i0 + mt * 16 + m)) * COUT_ + hh * 64;
#pragma unroll
        for (int nt = 0; nt < 4; ++nt) {
          const float v =
              acc[mt][nt][reg] + comb[hh][lane][mt * 16 + nt * 4 + reg];
          out[orow + nt * 16 + col] = v * linv;
        }
      }
    }
  }
}

// ---------------------------------------------------------------------------
extern "C" void kernel_launch(void* const* d_in, const int* in_sizes, int n_in,
                              void* d_out, int out_size, void* d_ws, size_t ws_size,
                              hipStream_t stream) {
  const float* x       = (const float*)d_in[0];
  const int*   adj     = (const int*)d_in[1];
  const float* W       = (const float*)d_in[2];
  const float* att_src = (const float*)d_in[3];
  const float* att_dst = (const float*)d_in[4];
  float* out = (float*)d_out;

  char* ws = (char*)d_ws;
  __bf16* hF = (__bf16*)ws;                                   // 8 MB frag-linear
  float2* aE = (float2*)(ws + (8u << 20));                    // 512 KB (E,E')
  float2* aF = (float2*)(ws + (9u << 20));                    // 512 KB (F,F')
  unsigned long long* abitsT =
      (unsigned long long*)(ws + (10u << 20));                // 4 MB transposed

  pack_kernel<<<(B_ * L_ * (L_ / 256)) / 4, 256, 0, stream>>>(adj, abitsT);
  proj_kernel<<<(B_ * L_) / TI, 256, 0, stream>>>(x, W, att_src, att_dst, hF, aE, aF);
  attn_kernel<<<B_ * (L_ / 32), 512, 0, stream>>>(hF, aE, aF, abitsT, out);
}

// Round 3
// 263.362 us; speedup vs baseline: 1.0327x; 1.0142x over previous
//
#include <hip/hip_runtime.h>

#define B_ 8
#define L_ 2048
#define CIN_ 256
#define COUT_ 256
#define HEADS_ 4
#define HD_ 64
#define NEG_SLOPE_ 0.2f
#define LOG2E_ 1.4426950408889634f

#define TI 32   // proj i-rows per block
#define TJ 64   // attn j-cols per tile
#define NJT (L_ / TJ)

typedef __attribute__((ext_vector_type(4))) float f32x4;
typedef __attribute__((ext_vector_type(8))) __bf16 bf16x8;
typedef __attribute__((ext_vector_type(4))) __bf16 bf16x4;

// MFMA 16x16x32 bf16 layouts (m89/m120-verified):
//  A[m][k]: m = lane&15, k = (lane>>4)*8 + e
//  B[k][n]: n = lane&15, k = (lane>>4)*8 + e
//  D[m][n]: n = lane&15, m = (lane>>4)*4 + reg
//
// hF ("B-frag-linear" h): for (b,h,jt,kt,nt) a 512-elem block, element
// (q*16+col)*8+e = h[channel h*64+nt*16+col][j = jt*64+kt*32+q*8+e].
// Rank-1 factorization: exp(leaky(a_i+d_j)) = max(E_i*F_j, E'_i*F'_j) — exact.
// abitsT transposed masks: abitsT[b][jw][row] (jw = j/64).
//
// R15: producer->consumer XCD alignment. attn pins batch b to XCD b
// (b = blockIdx&7, XCD = blockIdx%8). pack/proj now swizzle their block IDs
// so the blocks WRITING batch-b data also run on XCD b -> attn's ~550 MB of
// hF/aF re-reads hit the local 4 MB L2 instead of bouncing to the
// memory-side Infinity Cache (per-XCD L2s are not cross-coherent; dirty
// lines written on the wrong XCD force L3-path serving).

// ---------------------------------------------------------------------------
// Kernel 0: pack adj int32 -> 1 bit, TRANSPOSED layout abitsT[b][jw][row].
// Block swizzle: sbid = (bid&7)*4096 + bid>>3  =>  b = bid&7 = XCD.
// ---------------------------------------------------------------------------
__global__ __launch_bounds__(256, 4)
void pack_kernel(const int* __restrict__ adj, unsigned long long* __restrict__ abitsT) {
  const int sbid = ((blockIdx.x & 7) << 12) | (blockIdx.x >> 3);   // bijective, grid=32768
  const size_t wid = ((size_t)sbid * 256 + threadIdx.x) >> 6;      // 256-int chunk
  const int lane = threadIdx.x & 63;
  const int* p = adj + wid * 256 + lane;
  unsigned long long b0 = __ballot(p[0]   != 0);
  unsigned long long b1 = __ballot(p[64]  != 0);
  unsigned long long b2 = __ballot(p[128] != 0);
  unsigned long long b3 = __ballot(p[192] != 0);
  if (lane == 0) {
    const size_t row = wid >> 3;           // global row = b*2048 + i
    const int jw0 = (int)(wid & 7) * 4;    // first j-word of this chunk
    const size_t bb = row >> 11, l = row & 2047;
    unsigned long long* dst = abitsT + (bb << 16) + l;   // b*32*2048 + i
    dst[(size_t)(jw0 + 0) << 11] = b0;
    dst[(size_t)(jw0 + 1) << 11] = b1;
    dst[(size_t)(jw0 + 2) << 11] = b2;
    dst[(size_t)(jw0 + 3) << 11] = b3;
  }
}

// ---------------------------------------------------------------------------
// Kernel 1: h = x@W^T via MFMA -> hF (B-frag-linear bf16) + (E,E')/(F,F')
// factor pairs. grid 512 x 256 thr; block = 32 seq rows, wave w = head w.
// Block swizzle: sbid = (bid&7)*64 + bid>>3  =>  batch b = bid&7 = XCD,
// matching attn's consumer mapping.
// ---------------------------------------------------------------------------
__global__ __launch_bounds__(256, 2)
void proj_kernel(const float* __restrict__ x, const float* __restrict__ W,
                 const float* __restrict__ att_src, const float* __restrict__ att_dst,
                 __bf16* __restrict__ hF, float2* __restrict__ aE,
                 float2* __restrict__ aF) {
  __shared__ __align__(16) __bf16 Wl[COUT_][80];
  __shared__ __align__(16) __bf16 Al[2][2][512];

  const int tid = threadIdx.x;
  const int sbid = ((blockIdx.x & 7) << 6) | (blockIdx.x >> 3);    // bijective, grid=512
  const int r0 = sbid * TI;
  const int b  = r0 >> 11;
  const int l0 = r0 & (L_ - 1);

  const int w = tid >> 6, lane = tid & 63, col = lane & 15, q = lane >> 4;
  const int si = tid >> 3, soct = tid & 7;
  const int wn = tid >> 2, wkq = tid & 3;

  f32x4 acc[2][4];
#pragma unroll
  for (int mt = 0; mt < 2; ++mt)
#pragma unroll
    for (int nt = 0; nt < 4; ++nt) acc[mt][nt] = (f32x4)0.f;

  for (int kc = 0; kc < CIN_ / 64; ++kc) {
    __syncthreads();
#pragma unroll
    for (int rg = 0; rg < 4; ++rg) {
      const int row = rg * 64 + wn;
      const float4* ws = (const float4*)(W + (size_t)row * CIN_ + kc * 64 + wkq * 16);
#pragma unroll
      for (int u = 0; u < 4; ++u) {
        float4 f = ws[u];
        bf16x4 v;
        v[0] = (__bf16)f.x; v[1] = (__bf16)f.y; v[2] = (__bf16)f.z; v[3] = (__bf16)f.w;
        *(bf16x4*)&Wl[row][wkq * 16 + u * 4] = v;
      }
    }
    {
      const float4* xs = (const float4*)(x + (size_t)(r0 + si) * CIN_ + kc * 64 + soct * 8);
      float4 f0 = xs[0], f1 = xs[1];
      bf16x8 v;
      v[0] = (__bf16)f0.x; v[1] = (__bf16)f0.y; v[2] = (__bf16)f0.z; v[3] = (__bf16)f0.w;
      v[4] = (__bf16)f1.x; v[5] = (__bf16)f1.y; v[6] = (__bf16)f1.z; v[7] = (__bf16)f1.w;
      *(bf16x8*)&Al[si >> 4][soct >> 2][(((soct & 3) << 4) + (si & 15)) << 3] = v;
    }
    __syncthreads();

    bf16x8 af[2][2], bfr[2][4];
#pragma unroll
    for (int mt = 0; mt < 2; ++mt)
#pragma unroll
      for (int kt = 0; kt < 2; ++kt)
        af[mt][kt] = *(const bf16x8*)&Al[mt][kt][lane << 3];
#pragma unroll
    for (int kt = 0; kt < 2; ++kt)
#pragma unroll
      for (int nt = 0; nt < 4; ++nt)
        bfr[kt][nt] = *(const bf16x8*)&Wl[w * 64 + nt * 16 + col][kt * 32 + q * 8];
#pragma unroll
    for (int kt = 0; kt < 2; ++kt)
#pragma unroll
      for (int mt = 0; mt < 2; ++mt)
#pragma unroll
        for (int nt = 0; nt < 4; ++nt)
          acc[mt][nt] = __builtin_amdgcn_mfma_f32_16x16x32_bf16(
              af[mt][kt], bfr[kt][nt], acc[mt][nt], 0, 0, 0);
  }

  // ---- fused score factors ----
  float asv[4], adv[4];
#pragma unroll
  for (int nt = 0; nt < 4; ++nt) {
    asv[nt] = att_src[w * 64 + nt * 16 + col];
    adv[nt] = att_dst[w * 64 + nt * 16 + col];
  }
#pragma unroll
  for (int mt = 0; mt < 2; ++mt)
#pragma unroll
    for (int reg = 0; reg < 4; ++reg) {
      float s = 0.f, d = 0.f;
#pragma unroll
      for (int nt = 0; nt < 4; ++nt) {
        s = fmaf(acc[mt][nt][reg], asv[nt], s);
        d = fmaf(acc[mt][nt][reg], adv[nt], d);
      }
      s += __shfl_xor(s, 1, 64); d += __shfl_xor(d, 1, 64);
      s += __shfl_xor(s, 2, 64); d += __shfl_xor(d, 2, 64);
      s += __shfl_xor(s, 4, 64); d += __shfl_xor(d, 4, 64);
      s += __shfl_xor(s, 8, 64); d += __shfl_xor(d, 8, 64);
      if (col == 0) {
        int il = mt * 16 + q * 4 + reg;
        const size_t idx = ((size_t)(b * HEADS_ + w) << 11) + l0 + il;
        float2 ev, fv;
        ev.x = __builtin_exp2f(s * LOG2E_);
        ev.y = __builtin_exp2f(s * (LOG2E_ * NEG_SLOPE_));
        fv.x = __builtin_exp2f(d * LOG2E_);
        fv.y = __builtin_exp2f(d * (LOG2E_ * NEG_SLOPE_));
        aE[idx] = ev;
        aF[idx] = fv;
      }
    }

  // ---- hF write: D-frag -> B-frag-linear ----
  {
    const int jt_p = l0 >> 6;
    const int kt_p = (l0 >> 5) & 1;
    const int qhi = q >> 1, qlo = q & 1;
#pragma unroll
    for (int mt = 0; mt < 2; ++mt) {
      const int qp = mt * 2 + qhi;
#pragma unroll
      for (int nt = 0; nt < 4; ++nt) {
        bf16x4 v;
        v[0] = (__bf16)acc[mt][nt][0];
        v[1] = (__bf16)acc[mt][nt][1];
        v[2] = (__bf16)acc[mt][nt][2];
        v[3] = (__bf16)acc[mt][nt][3];
        const size_t off =
            ((((size_t)(b * HEADS_ + w) * 32 + jt_p) * 2 + kt_p) * 4 + nt) * 512 +
            (qp * 16 + col) * 8 + qlo * 4;
        *(bf16x4*)(hF + off) = v;
      }
    }
  }
}

// ---------------------------------------------------------------------------
// Kernel 2 (R12 verbatim — measured-best attn structure): split-j attention,
// no launch-bounds VGPR cap. 512 thr = 8 waves = 4 heads x 2 j-halves;
// partial (O,l) combined via LDS + one barrier.
// ---------------------------------------------------------------------------
__global__ __launch_bounds__(512)
void attn_kernel(const __bf16* __restrict__ hF, const float2* __restrict__ aE,
                 const float2* __restrict__ aF,
                 const unsigned long long* __restrict__ abitsT,
                 float* __restrict__ out) {
  __shared__ __align__(16) float comb[HEADS_][64][40];   // 40 KB combine buf

  const int tid = threadIdx.x;
  const int b  = blockIdx.x & 7;           // XCD swizzle
  const int i0 = (blockIdx.x >> 3) * 32;

  const int w = tid >> 6, lane = tid & 63, col = lane & 15, q = lane >> 4;
  const int hh = w & 3;                    // head
  const int jh = w >> 2;                   // j-half
  const int jt0 = jh * (NJT / 2), jt1 = jt0 + NJT / 2;

  const size_t hl = (size_t)(b * HEADS_ + hh);
  const float2 EE[2] = {aE[(hl << 11) + i0 + col],
                        aE[(hl << 11) + i0 + 16 + col]};
  const float* afb = (const float*)(aF + (hl << 11)) + q * 16;
  const __bf16* hb = hF + hl * 131072 + lane * 8;
  const unsigned long long* mb = abitsT + ((size_t)b << 16) + i0 + col;

  bf16x8 bones;
#pragma unroll
  for (int e = 0; e < 8; ++e) bones[e] = (__bf16)1.0f;

  f32x4 acc[2][4], accl[2];
#pragma unroll
  for (int mt = 0; mt < 2; ++mt) {
    accl[mt] = (f32x4)0.f;
#pragma unroll
    for (int nt = 0; nt < 4; ++nt) acc[mt][nt] = (f32x4)0.f;
  }

  unsigned long long cm0 = mb[(size_t)jt0 << 11];
  unsigned long long cm1 = mb[((size_t)jt0 << 11) + 16];

  for (int jt = jt0; jt < jt1; ++jt) {
    const int jn = (jt < jt1 - 1) ? jt + 1 : jt;
    const unsigned long long nm0 = mb[(size_t)jn << 11];
    const unsigned long long nm1 = mb[((size_t)jn << 11) + 16];

    // per-kt: load 4 cb frags + 4 cf float4s, build av for both mt, 10 MFMAs.
#pragma unroll
    for (int kt = 0; kt < 2; ++kt) {
      bf16x8 cb0 = *(const bf16x8*)(hb + jt * 4096 + (kt * 4 + 0) * 512);
      bf16x8 cb1 = *(const bf16x8*)(hb + jt * 4096 + (kt * 4 + 1) * 512);
      bf16x8 cb2 = *(const bf16x8*)(hb + jt * 4096 + (kt * 4 + 2) * 512);
      bf16x8 cb3 = *(const bf16x8*)(hb + jt * 4096 + (kt * 4 + 3) * 512);
      float cf[16];
#pragma unroll
      for (int u = 0; u < 4; ++u)
        *(float4*)&cf[u * 4] =
            *(const float4*)(afb + jt * 128 + kt * 64 + u * 4);

      bf16x8 av[2];
#pragma unroll
      for (int mt = 0; mt < 2; ++mt) {
        const unsigned long long bw = mt ? cm1 : cm0;
        const unsigned int tsh = ((unsigned int)(bw >> (kt * 32))) >> (q * 8);
        const float Ex = EE[mt].x, Ey = EE[mt].y;
#pragma unroll
        for (int e = 0; e < 8; ++e) {
          const float m1 = Ex * cf[2 * e];
          const float m2 = Ey * cf[2 * e + 1];
          const float pm = fmaxf(m1, m2);
          const float p = (tsh & (1u << e)) ? pm : 0.f;
          av[mt][e] = (__bf16)p;
        }
      }
#pragma unroll
      for (int mt = 0; mt < 2; ++mt) {
        acc[mt][0] = __builtin_amdgcn_mfma_f32_16x16x32_bf16(av[mt], cb0, acc[mt][0], 0, 0, 0);
        acc[mt][1] = __builtin_amdgcn_mfma_f32_16x16x32_bf16(av[mt], cb1, acc[mt][1], 0, 0, 0);
        acc[mt][2] = __builtin_amdgcn_mfma_f32_16x16x32_bf16(av[mt], cb2, acc[mt][2], 0, 0, 0);
        acc[mt][3] = __builtin_amdgcn_mfma_f32_16x16x32_bf16(av[mt], cb3, acc[mt][3], 0, 0, 0);
        accl[mt] = __builtin_amdgcn_mfma_f32_16x16x32_bf16(av[mt], bones, accl[mt], 0, 0, 0);
      }
    }

    cm0 = nm0; cm1 = nm1;
  }

  // ---- combine j-halves via LDS ----
  if (jh == 1) {
#pragma unroll
    for (int mt = 0; mt < 2; ++mt)
#pragma unroll
      for (int nt = 0; nt < 4; ++nt)
        *(f32x4*)&comb[hh][lane][mt * 16 + nt * 4] = acc[mt][nt];
    *(f32x4*)&comb[hh][lane][32] = accl[0];
    *(f32x4*)&comb[hh][lane][36] = accl[1];
  }
  __syncthreads();
  if (jh == 0) {
#pragma unroll
    for (int mt = 0; mt < 2; ++mt) {
      const f32x4 lo = accl[mt] + *(const f32x4*)&comb[hh][lane][32 + mt * 4];
#pragma unroll
      for (int reg = 0; reg < 4; ++reg) {
        const int m = q * 4 + reg;
        const float linv = 1.0f / lo[reg];
        const size_t orow =
            ((size_t)(b * L_ + i0 + mt * 16 + m)) * COUT_ + hh * 64;
#pragma unroll
        for (int nt = 0; nt < 4; ++nt) {
          const float v =
              acc[mt][nt][reg] + comb[hh][lane][mt * 16 + nt * 4 + reg];
          out[orow + nt * 16 + col] = v * linv;
        }
      }
    }
  }
}

// ---------------------------------------------------------------------------
extern "C" void kernel_launch(void* const* d_in, const int* in_sizes, int n_in,
                              void* d_out, int out_size, void* d_ws, size_t ws_size,
                              hipStream_t stream) {
  const float* x       = (const float*)d_in[0];
  const int*   adj     = (const int*)d_in[1];
  const float* W       = (const float*)d_in[2];
  const float* att_src = (const float*)d_in[3];
  const float* att_dst = (const float*)d_in[4];
  float* out = (float*)d_out;

  char* ws = (char*)d_ws;
  __bf16* hF = (__bf16*)ws;                                   // 8 MB frag-linear
  float2* aE = (float2*)(ws + (8u << 20));                    // 512 KB (E,E')
  float2* aF = (float2*)(ws + (9u << 20));                    // 512 KB (F,F')
  unsigned long long* abitsT =
      (unsigned long long*)(ws + (10u << 20));                // 4 MB transposed

  pack_kernel<<<(B_ * L_ * (L_ / 256)) / 4, 256, 0, stream>>>(adj, abitsT);
  proj_kernel<<<(B_ * L_) / TI, 256, 0, stream>>>(x, W, att_src, att_dst, hF, aE, aF);
  attn_kernel<<<B_ * (L_ / 32), 512, 0, stream>>>(hF, aE, aF, abitsT, out);
}